// Round 7
// baseline (437.943 us; speedup 1.0000x reference)
//
#include <hip/hip_runtime.h>
#include <hip/hip_bf16.h>
#include <stdint.h>

// Problem dims (fixed by setup_inputs)
#define T_DIM 2048
#define I_DIM 4096
#define O_DIM 4096
#define R_DIM 16
#define QBLK  32

typedef __bf16 bf16x8 __attribute__((ext_vector_type(8)));
typedef float  floatx4 __attribute__((ext_vector_type(4)));
typedef unsigned short ushort_t;

#define AS1 __attribute__((address_space(1)))
#define AS3 __attribute__((address_space(3)))

__device__ __forceinline__ ushort_t f2bf(float f) {
  unsigned u = __float_as_uint(f);
  u += 0x7FFFu + ((u >> 16) & 1u);   // round-to-nearest-even
  return (ushort_t)(u >> 16);
}

__device__ __forceinline__ float dot4(float4 a, float4 b) {
  return a.x * b.x + a.y * b.y + a.z * b.z + a.w * b.w;
}

// ---------------- k_stream: xb=bf16(x) | wb=dequant(q). ZERO LDS. ------
__global__ __launch_bounds__(256) void k_stream(const float* __restrict__ x,
                                                const int* __restrict__ q,
                                                const float* __restrict__ scales,
                                                ushort_t* __restrict__ xb,
                                                ushort_t* __restrict__ wb) {
  const int b = blockIdx.x, tid = threadIdx.x;
  if (b < 4096) {                             // ---- prep_x
    int idx = b * 256 + tid;                  // 8-element chunk id
    const float4* xp = (const float4*)x;
    float4 a = xp[idx * 2], c = xp[idx * 2 + 1];
    union { ushort_t u[8]; uint4 v; } r;
    r.u[0] = f2bf(a.x); r.u[1] = f2bf(a.y); r.u[2] = f2bf(a.z); r.u[3] = f2bf(a.w);
    r.u[4] = f2bf(c.x); r.u[5] = f2bf(c.y); r.u[6] = f2bf(c.z); r.u[7] = f2bf(c.w);
    ((uint4*)xb)[idx] = r.v;
    return;
  }
  {                                           // ---- prep_w
    int idx = (b - 4096) * 256 + tid;
    int o  = idx >> 9;
    int i0 = (idx & 511) * 8;
    float s = scales[o * (I_DIM / QBLK) + (i0 >> 5)];
    const int4* qp = (const int4*)(q + (size_t)o * I_DIM + i0);
    int4 q0 = qp[0], q1 = qp[1];
    union { ushort_t u[8]; uint4 v; } r;
    r.u[0] = f2bf((float)(q0.x - 8) * s); r.u[1] = f2bf((float)(q0.y - 8) * s);
    r.u[2] = f2bf((float)(q0.z - 8) * s); r.u[3] = f2bf((float)(q0.w - 8) * s);
    r.u[4] = f2bf((float)(q1.x - 8) * s); r.u[5] = f2bf((float)(q1.y - 8) * s);
    r.u[6] = f2bf((float)(q1.z - 8) * s); r.u[7] = f2bf((float)(q1.w - 8) * s);
    ((uint4*)wb)[idx] = r.v;
  }
}

// ---------------- k_xd: xd = alpha * (x @ down^T) ----------------------
__global__ __launch_bounds__(256) void k_xd(const float* __restrict__ x,
                                            const float* __restrict__ down,
                                            const float* __restrict__ alphap,
                                            float* __restrict__ xd) {
  __shared__ float ds[16 * 512];              // 32 KB
  const int b = blockIdx.x, tid = threadIdx.x;
  const int tl = tid >> 5, s = tid & 31;
  const int t = b * 8 + tl;
  float acc[16];
#pragma unroll
  for (int r = 0; r < 16; ++r) acc[r] = 0.f;
  for (int c = 0; c < 8; ++c) {
    const int ib = c * 512;
    __syncthreads();
#pragma unroll
    for (int j = 0; j < 8; ++j) {
      int e = j * 256 + tid;
      int r = e >> 7, col = e & 127;
      ((float4*)ds)[e] = ((const float4*)(down + (size_t)r * I_DIM + ib))[col];
    }
    __syncthreads();
#pragma unroll
    for (int j = 0; j < 4; ++j) {
      float4 xv = ((const float4*)(x + (size_t)t * I_DIM + ib))[s + 32 * j];
#pragma unroll
      for (int r = 0; r < 16; ++r) {
        float4 dv = ((const float4*)ds)[r * 128 + s + 32 * j];
        acc[r] += dot4(xv, dv);
      }
    }
  }
  const float al = alphap[0];
#pragma unroll
  for (int r = 0; r < 16; ++r) {
    float v = acc[r];
    v += __shfl_down(v, 16, 32);
    v += __shfl_down(v, 8, 32);
    v += __shfl_down(v, 4, 32);
    v += __shfl_down(v, 2, 32);
    v += __shfl_down(v, 1, 32);
    if (s == 0) xd[t * 16 + r] = v * al;
  }
}

// ======================= R12 main GEMM =================================
// Invariant found across R5-R11: EVERY kernel measured exactly 8 waves/CU
// (Occupancy ~23%). All carried ~128 VGPR + 64 AGPR (acc[4][4]) = ~192
// unified regs/wave -> the 129-256 register class caps at 8 waves/CU
// (m69: waves halve at 64/128/256; gfx950 AGPR shares the budget). At 8
// waves/CU this shape is latency-bound (~5-7 B/cy/CU global) -- m102's
// N=2048 cliff reproduced. R12 halves per-wave registers to enter the
// <=128 class -> 16 waves/CU:
//  - wave-out 64x32: acc[4][2] = 32 AGPR; frags af[4]+bf[2] = 48 VGPR.
//  - __launch_bounds__(512, 4): 4 waves/EU = 16 waves/CU target.
//  - Tile 128x128, 512 thr / 8 waves (2M x 4N), BK=64, grid (32,16)=512
//    blocks -> 2 blocks/CU co-resident.
//  - SINGLE-buffered 32KB LDS, plain m97-style 2-barrier loop: the
//    vmcnt(0) drain at the barrier is hidden by the OTHER resident
//    block's waves (m97's mechanism, 874 TF at 12 waves/CU).
//  - Both-sides XOR granule swizzle (0 conflicts, R8-verified).
//  - C/D layout + fragment indexing verified R5-R11 (passed each round).

__global__ __launch_bounds__(512, 4) void k_gemm(const ushort_t* __restrict__ xb,
                                                 const ushort_t* __restrict__ wb,
                                                 const float* __restrict__ bias,
                                                 const float* __restrict__ xd,
                                                 const float* __restrict__ up,
                                                 float* __restrict__ y) {
  __shared__ __align__(16) ushort_t As[128 * 64];   // 16 KB
  __shared__ __align__(16) ushort_t Bs[128 * 64];   // 16 KB

  const int tid = threadIdx.x;
  const int wv = tid >> 6, lane = tid & 63;
  const int quad = lane >> 4, m16 = lane & 15;
  const int wm = wv >> 2, wn = wv & 3;        // 2(M) x 4(N) waves

  const int oT = blockIdx.x * 128, tT = blockIdx.y * 128;
  const ushort_t* ap = xb + (size_t)tT * I_DIM;
  const ushort_t* bp = wb + (size_t)oT * I_DIM;

  floatx4 acc[4][2] = {};

  for (int kt = 0; kt < I_DIM / 64; ++kt) {
    const int k0 = kt * 64;
    // Stage A then B: each 128x64 bf16 = 1024 granules; 2 loads/thread.
    // LDS dest linear in seg; global col-granule pre-swizzled g^(r&7).
#pragma unroll
    for (int it = 0; it < 2; ++it) {
      const int seg = it * 512 + tid;
      const int r = seg >> 3, cg = (seg & 7) ^ (r & 7);
      __builtin_amdgcn_global_load_lds(
          (const AS1 char*)(ap + (size_t)r * I_DIM + k0 + cg * 8),
          (AS3 char*)(As + (size_t)seg * 8), 16, 0, 0);
    }
#pragma unroll
    for (int it = 0; it < 2; ++it) {
      const int seg = it * 512 + tid;
      const int r = seg >> 3, cg = (seg & 7) ^ (r & 7);
      __builtin_amdgcn_global_load_lds(
          (const AS1 char*)(bp + (size_t)r * I_DIM + k0 + cg * 8),
          (AS3 char*)(Bs + (size_t)seg * 8), 16, 0, 0);
    }
    __syncthreads();   // vmcnt(0) drain; hidden by the other resident block

#pragma unroll
    for (int ks2 = 0; ks2 < 2; ++ks2) {              // two K=32 halves
      const int c = ks2 * 4 + quad;
      bf16x8 af[4], bfr[2];
#pragma unroll
      for (int im = 0; im < 4; ++im) {
        const int m = wm * 64 + im * 16 + m16;
        af[im] = *(const bf16x8*)(As + (m * 8 + (c ^ (m & 7))) * 8);
      }
#pragma unroll
      for (int in_ = 0; in_ < 2; ++in_) {
        const int n = wn * 32 + in_ * 16 + m16;
        bfr[in_] = *(const bf16x8*)(Bs + (n * 8 + (c ^ (n & 7))) * 8);
      }
#pragma unroll
      for (int im = 0; im < 4; ++im)
#pragma unroll
        for (int in_ = 0; in_ < 2; ++in_)
          acc[im][in_] = __builtin_amdgcn_mfma_f32_16x16x32_bf16(
              af[im], bfr[in_], acc[im][in_], 0, 0, 0);
    }
    __syncthreads();
  }

  // Epilogue: y[t][o] = acc + dot16(xd[t], up[o]) + bias[o]
  // C/D layout: row = quad*4+reg, col = lane&15 (m89-verified).
#pragma unroll
  for (int im = 0; im < 4; ++im) {
#pragma unroll
    for (int reg = 0; reg < 4; ++reg) {
      const int t = tT + wm * 64 + im * 16 + quad * 4 + reg;
      const float4* xr = (const float4*)(xd + t * 16);
      float4 x0 = xr[0], x1 = xr[1], x2 = xr[2], x3 = xr[3];
#pragma unroll
      for (int in_ = 0; in_ < 2; ++in_) {
        const int o = oT + wn * 32 + in_ * 16 + m16;
        const float4* ur = (const float4*)(up + (size_t)o * R_DIM);
        float lv = dot4(x0, ur[0]) + dot4(x1, ur[1]) +
                   dot4(x2, ur[2]) + dot4(x3, ur[3]);
        y[(size_t)t * O_DIM + o] = acc[im][in_][reg] + lv + bias[o];
      }
    }
  }
}

extern "C" void kernel_launch(void* const* d_in, const int* in_sizes, int n_in,
                              void* d_out, int out_size, void* d_ws, size_t ws_size,
                              hipStream_t stream) {
  const float* x      = (const float*)d_in[0];
  const int*   q      = (const int*)d_in[1];
  const float* scales = (const float*)d_in[2];
  const float* up     = (const float*)d_in[3];
  const float* down   = (const float*)d_in[4];
  const float* alpha  = (const float*)d_in[5];
  const float* bias   = (const float*)d_in[6];
  float* y = (float*)d_out;

  // ws layout: xb bf16 [T,I] (16 MB) | wb bf16 [O,I] (32 MB) | xd f32 [T,16]
  ushort_t* xb = (ushort_t*)d_ws;
  ushort_t* wb = (ushort_t*)((char*)d_ws + (size_t)T_DIM * I_DIM * 2);
  float*    xd = (float*)((char*)d_ws + (size_t)T_DIM * I_DIM * 2 + (size_t)O_DIM * I_DIM * 2);

  hipLaunchKernelGGL(k_stream, dim3(4096 + 8192), dim3(256), 0, stream,
                     x, q, scales, xb, wb);
  hipLaunchKernelGGL(k_xd, dim3(256), dim3(256), 0, stream, x, down, alpha, xd);
  hipLaunchKernelGGL(k_gemm, dim3(O_DIM / 128, T_DIM / 128), dim3(512), 0, stream,
                     xb, wb, bias, xd, up, y);
}

// Round 8
// 426.506 us; speedup vs baseline: 1.0268x; 1.0268x over previous
//
#include <hip/hip_runtime.h>
#include <hip/hip_bf16.h>
#include <stdint.h>

// Problem dims (fixed by setup_inputs)
#define T_DIM 2048
#define I_DIM 4096
#define O_DIM 4096
#define R_DIM 16
#define QBLK  32

typedef __bf16 bf16x8 __attribute__((ext_vector_type(8)));
typedef float  floatx4 __attribute__((ext_vector_type(4)));
typedef unsigned short ushort_t;

#define AS1 __attribute__((address_space(1)))
#define AS3 __attribute__((address_space(3)))

__device__ __forceinline__ ushort_t f2bf(float f) {
  unsigned u = __float_as_uint(f);
  u += 0x7FFFu + ((u >> 16) & 1u);   // round-to-nearest-even
  return (ushort_t)(u >> 16);
}

__device__ __forceinline__ float dot4(float4 a, float4 b) {
  return a.x * b.x + a.y * b.y + a.z * b.z + a.w * b.w;
}

// ---------------- k_stream (R13): xb=bf16(x) | wb=dequant(q) -----------
// R5-R12 prep was structure-invariant at ~150us = ~1 TB/s (6x below the
// 6.3 TB/s streaming ceiling). Common defect: 32B of load in flight per
// thread with a dependent convert chain. R13: grid-stride units of 16
// elements; each thread issues 4 x 64B contiguous loads (256B in flight)
// BEFORE any convert, then converts + stores 4 x 32B. Arithmetic is
// bit-identical to R5-R12 (same (q-8)*s, same RNE bf16 round).
// Blocks [0,512): x units (T*I/16 = 524288 = 512*256*4).
// Blocks [512,1536): q units (O*I/16 = 1048576 = 1024*256*4).
__global__ __launch_bounds__(256) void k_stream(const float* __restrict__ x,
                                                const int* __restrict__ q,
                                                const float* __restrict__ scales,
                                                ushort_t* __restrict__ xb,
                                                ushort_t* __restrict__ wb) {
  const int b = blockIdx.x, tid = threadIdx.x;
  if (b < 512) {                              // ---- prep_x
    const int stride = 512 * 256;             // units per sweep
    const int u0 = b * 256 + tid;
    float4 v[4][4];
#pragma unroll
    for (int j = 0; j < 4; ++j) {             // 4 x 64B loads in flight
      const float4* p = (const float4*)x + (size_t)(u0 + j * stride) * 4;
      v[j][0] = p[0]; v[j][1] = p[1]; v[j][2] = p[2]; v[j][3] = p[3];
    }
#pragma unroll
    for (int j = 0; j < 4; ++j) {
      const size_t u = u0 + (size_t)j * stride;
      union { ushort_t us[16]; uint4 o[2]; } r;
#pragma unroll
      for (int k = 0; k < 4; ++k) {
        r.us[k * 4 + 0] = f2bf(v[j][k].x); r.us[k * 4 + 1] = f2bf(v[j][k].y);
        r.us[k * 4 + 2] = f2bf(v[j][k].z); r.us[k * 4 + 3] = f2bf(v[j][k].w);
      }
      ((uint4*)xb)[u * 2] = r.o[0];
      ((uint4*)xb)[u * 2 + 1] = r.o[1];
    }
    return;
  }
  {                                           // ---- prep_w
    const int stride = 1024 * 256;
    const int u0 = (b - 512) * 256 + tid;
    int4 v[4][4];
    float s[4];
#pragma unroll
    for (int j = 0; j < 4; ++j) {             // 4 x 64B loads in flight
      const size_t u = u0 + (size_t)j * stride;
      const int4* p = (const int4*)q + u * 4;
      v[j][0] = p[0]; v[j][1] = p[1]; v[j][2] = p[2]; v[j][3] = p[3];
      const size_t e = u * 16;                // element index in [O*I)
      s[j] = scales[(e >> 12) * (I_DIM / QBLK) + ((e & 4095) >> 5)];
    }
#pragma unroll
    for (int j = 0; j < 4; ++j) {
      const size_t u = u0 + (size_t)j * stride;
      const float sj = s[j];
      union { ushort_t us[16]; uint4 o[2]; } r;
#pragma unroll
      for (int k = 0; k < 4; ++k) {
        r.us[k * 4 + 0] = f2bf((float)(v[j][k].x - 8) * sj);
        r.us[k * 4 + 1] = f2bf((float)(v[j][k].y - 8) * sj);
        r.us[k * 4 + 2] = f2bf((float)(v[j][k].z - 8) * sj);
        r.us[k * 4 + 3] = f2bf((float)(v[j][k].w - 8) * sj);
      }
      ((uint4*)wb)[u * 2] = r.o[0];
      ((uint4*)wb)[u * 2 + 1] = r.o[1];
    }
  }
}

// ---------------- k_xd: xd = alpha * (x @ down^T) ----------------------
__global__ __launch_bounds__(256) void k_xd(const float* __restrict__ x,
                                            const float* __restrict__ down,
                                            const float* __restrict__ alphap,
                                            float* __restrict__ xd) {
  __shared__ float ds[16 * 512];              // 32 KB
  const int b = blockIdx.x, tid = threadIdx.x;
  const int tl = tid >> 5, s = tid & 31;
  const int t = b * 8 + tl;
  float acc[16];
#pragma unroll
  for (int r = 0; r < 16; ++r) acc[r] = 0.f;
  for (int c = 0; c < 8; ++c) {
    const int ib = c * 512;
    __syncthreads();
#pragma unroll
    for (int j = 0; j < 8; ++j) {
      int e = j * 256 + tid;
      int r = e >> 7, col = e & 127;
      ((float4*)ds)[e] = ((const float4*)(down + (size_t)r * I_DIM + ib))[col];
    }
    __syncthreads();
#pragma unroll
    for (int j = 0; j < 4; ++j) {
      float4 xv = ((const float4*)(x + (size_t)t * I_DIM + ib))[s + 32 * j];
#pragma unroll
      for (int r = 0; r < 16; ++r) {
        float4 dv = ((const float4*)ds)[r * 128 + s + 32 * j];
        acc[r] += dot4(xv, dv);
      }
    }
  }
  const float al = alphap[0];
#pragma unroll
  for (int r = 0; r < 16; ++r) {
    float v = acc[r];
    v += __shfl_down(v, 16, 32);
    v += __shfl_down(v, 8, 32);
    v += __shfl_down(v, 4, 32);
    v += __shfl_down(v, 2, 32);
    v += __shfl_down(v, 1, 32);
    if (s == 0) xd[t * 16 + r] = v * al;
  }
}

// ======================= main GEMM (R9/R11 verbatim, best: 276us) ======
// Kill-list: schedules (R6-R9), ws round-trip (R10), XCD locality (R11),
// bank conflicts (R8: 0), occupancy (R12: 2x waves, no change). Remaining
// invariant: staged-operand delivery 4.6-6.2 B/cy/CU vs m97@4096's 21.8.
// GEMM held constant this round while prep is fixed.

#define BK 64
#define NT (I_DIM / BK)        // 64 K-tiles
#define ASZ (128 * BK)         // A tile elems (16KB)
#define BSZ (256 * BK)         // B tile elems (32KB)

__device__ __forceinline__ bf16x8 lds_read16(unsigned addr) {
  bf16x8 d;
  asm volatile("ds_read_b128 %0, %1" : "=v"(d) : "v"(addr));
  return d;
}

__device__ __forceinline__ void stage6(const ushort_t* __restrict__ ga,
                                       const ushort_t* __restrict__ gb,
                                       ushort_t* Ast, ushort_t* Bst, int tid) {
#pragma unroll
  for (int it = 0; it < 2; ++it) {
    const int seg = it * 512 + tid;
    const int r = seg >> 3, cg = (seg & 7) ^ (r & 7);
    __builtin_amdgcn_global_load_lds(
        (const AS1 char*)(ga + (size_t)r * I_DIM + cg * 8),
        (AS3 char*)(Ast + (size_t)seg * 8), 16, 0, 0);
  }
#pragma unroll
  for (int it = 0; it < 4; ++it) {
    const int seg = it * 512 + tid;
    const int r = seg >> 3, cg = (seg & 7) ^ (r & 7);
    __builtin_amdgcn_global_load_lds(
        (const AS1 char*)(gb + (size_t)r * I_DIM + cg * 8),
        (AS3 char*)(Bst + (size_t)seg * 8), 16, 0, 0);
  }
}

template<int VM, bool STG>
__device__ __forceinline__ void ktile(unsigned aB, unsigned bB,
                                      ushort_t* Ast, ushort_t* Bst,
                                      const ushort_t* ga, const ushort_t* gb,
                                      floatx4 (&acc)[4][4], int tid) {
  const int lane = tid & 63, wv = tid >> 6;
  const int quad = lane >> 4, m16 = lane & 15;
  const int wm = wv >> 2, wn = wv & 3;

  if constexpr (STG) stage6(ga, gb, Ast, Bst, tid);

  bf16x8 a0[4], b0[4], a1[4], b1[4];
#pragma unroll
  for (int i = 0; i < 4; ++i) {
    const int m = wm * 64 + i * 16 + m16;
    a0[i] = lds_read16(aB + (unsigned)((m * 8 + (quad ^ (m & 7))) * 16));
  }
#pragma unroll
  for (int i = 0; i < 4; ++i) {
    const int n = wn * 64 + i * 16 + m16;
    b0[i] = lds_read16(bB + (unsigned)((n * 8 + (quad ^ (n & 7))) * 16));
  }
#pragma unroll
  for (int i = 0; i < 4; ++i) {
    const int m = wm * 64 + i * 16 + m16;
    a1[i] = lds_read16(aB + (unsigned)((m * 8 + ((4 + quad) ^ (m & 7))) * 16));
  }
#pragma unroll
  for (int i = 0; i < 4; ++i) {
    const int n = wn * 64 + i * 16 + m16;
    b1[i] = lds_read16(bB + (unsigned)((n * 8 + ((4 + quad) ^ (n & 7))) * 16));
  }
  asm volatile("s_waitcnt lgkmcnt(8)" ::: "memory");
  __builtin_amdgcn_sched_barrier(0);
  __builtin_amdgcn_s_setprio(1);
#pragma unroll
  for (int i = 0; i < 4; ++i)
#pragma unroll
    for (int j = 0; j < 4; ++j)
      acc[i][j] = __builtin_amdgcn_mfma_f32_16x16x32_bf16(a0[i], b0[j], acc[i][j], 0, 0, 0);
  __builtin_amdgcn_s_setprio(0);
  asm volatile("s_waitcnt lgkmcnt(0)" ::: "memory");
  __builtin_amdgcn_sched_barrier(0);
  __builtin_amdgcn_s_setprio(1);
#pragma unroll
  for (int i = 0; i < 4; ++i)
#pragma unroll
    for (int j = 0; j < 4; ++j)
      acc[i][j] = __builtin_amdgcn_mfma_f32_16x16x32_bf16(a1[i], b1[j], acc[i][j], 0, 0, 0);
  __builtin_amdgcn_s_setprio(0);
  if constexpr (VM == 6)      asm volatile("s_waitcnt vmcnt(6)" ::: "memory");
  else if constexpr (VM == 0) asm volatile("s_waitcnt vmcnt(0)" ::: "memory");
  if constexpr (VM >= 0) __builtin_amdgcn_sched_barrier(0);
  __builtin_amdgcn_s_barrier();
}

__global__ __launch_bounds__(512, 2) void k_gemm(const ushort_t* __restrict__ xb,
                                                 const ushort_t* __restrict__ wb,
                                                 const float* __restrict__ bias,
                                                 const float* __restrict__ xd,
                                                 const float* __restrict__ up,
                                                 float* __restrict__ y) {
  __shared__ __align__(16) ushort_t As[3][ASZ];   // 48 KB
  __shared__ __align__(16) ushort_t Bs[3][BSZ];   // 96 KB

  const int tid = threadIdx.x;

  const int id = blockIdx.x;
  const int xcd = id & 7, slot = id >> 3;
  const int bx = xcd * 2 + (slot & 1);      // O tile [0,16)
  const int by = slot >> 1;                 // T tile [0,16)
  const int oT = bx * 256, tT = by * 128;

  const ushort_t* ap = xb + (size_t)tT * I_DIM;
  const ushort_t* bp = wb + (size_t)oT * I_DIM;

  const unsigned aL = (unsigned)(uintptr_t)(AS3 ushort_t*)&As[0][0];
  const unsigned bL = (unsigned)(uintptr_t)(AS3 ushort_t*)&Bs[0][0];
  const unsigned aS0 = aL, aS1 = aL + ASZ * 2, aS2 = aL + ASZ * 4;
  const unsigned bS0 = bL, bS1 = bL + BSZ * 2, bS2 = bL + BSZ * 4;

  floatx4 acc[4][4] = {};

  stage6(ap, bp, As[0], Bs[0], tid);
  stage6(ap + BK, bp + BK, As[1], Bs[1], tid);
  asm volatile("s_waitcnt vmcnt(6)" ::: "memory");
  __builtin_amdgcn_sched_barrier(0);
  __builtin_amdgcn_s_barrier();

  int kc = 2 * BK;
  for (int g = 0; g < 20; ++g) {
    ktile<6, true>(aS0, bS0, As[2], Bs[2], ap + kc, bp + kc, acc, tid); kc += BK;
    ktile<6, true>(aS1, bS1, As[0], Bs[0], ap + kc, bp + kc, acc, tid); kc += BK;
    ktile<6, true>(aS2, bS2, As[1], Bs[1], ap + kc, bp + kc, acc, tid); kc += BK;
  }
  ktile<6, true>(aS0, bS0, As[2], Bs[2], ap + kc, bp + kc, acc, tid); kc += BK;
  ktile<6, true>(aS1, bS1, As[0], Bs[0], ap + kc, bp + kc, acc, tid);
  ktile<0, false>(aS2, bS2, nullptr, nullptr, nullptr, nullptr, acc, tid);
  ktile<-1, false>(aS0, bS0, nullptr, nullptr, nullptr, nullptr, acc, tid);

  // Epilogue: y[t][o] = acc + dot16(xd[t], up[o]) + bias[o]
  const int lane = tid & 63, wv = tid >> 6;
  const int quad = lane >> 4, m16 = lane & 15;
  const int wm = wv >> 2, wn = wv & 3;
#pragma unroll
  for (int im = 0; im < 4; ++im) {
#pragma unroll
    for (int reg = 0; reg < 4; ++reg) {
      const int t = tT + wm * 64 + im * 16 + quad * 4 + reg;
      const float4* xr = (const float4*)(xd + t * 16);
      float4 x0 = xr[0], x1 = xr[1], x2 = xr[2], x3 = xr[3];
#pragma unroll
      for (int in_ = 0; in_ < 4; ++in_) {
        const int o = oT + wn * 64 + in_ * 16 + m16;
        const float4* ur = (const float4*)(up + (size_t)o * R_DIM);
        float lv = dot4(x0, ur[0]) + dot4(x1, ur[1]) +
                   dot4(x2, ur[2]) + dot4(x3, ur[3]);
        y[(size_t)t * O_DIM + o] = acc[im][in_][reg] + lv + bias[o];
      }
    }
  }
}

extern "C" void kernel_launch(void* const* d_in, const int* in_sizes, int n_in,
                              void* d_out, int out_size, void* d_ws, size_t ws_size,
                              hipStream_t stream) {
  const float* x      = (const float*)d_in[0];
  const int*   q      = (const int*)d_in[1];
  const float* scales = (const float*)d_in[2];
  const float* up     = (const float*)d_in[3];
  const float* down   = (const float*)d_in[4];
  const float* alpha  = (const float*)d_in[5];
  const float* bias   = (const float*)d_in[6];
  float* y = (float*)d_out;

  // ws layout: xb bf16 [T,I] (16 MB) | wb bf16 [O,I] (32 MB) | xd f32 [T,16]
  ushort_t* xb = (ushort_t*)d_ws;
  ushort_t* wb = (ushort_t*)((char*)d_ws + (size_t)T_DIM * I_DIM * 2);
  float*    xd = (float*)((char*)d_ws + (size_t)T_DIM * I_DIM * 2 + (size_t)O_DIM * I_DIM * 2);

  hipLaunchKernelGGL(k_xd, dim3(256), dim3(256), 0, stream, x, down, alpha, xd);
  hipLaunchKernelGGL(k_stream, dim3(1536), dim3(256), 0, stream,
                     x, q, scales, xb, wb);
  hipLaunchKernelGGL(k_gemm, dim3((O_DIM / 256) * (T_DIM / 128)), dim3(512), 0, stream,
                     xb, wb, bias, xd, up, y);
}